// Round 12
// baseline (177.821 us; speedup 1.0000x reference)
//
#include <hip/hip_runtime.h>
#include <hip/hip_bf16.h>
#include <math.h>

typedef __bf16 bf16_t;
typedef __bf16 bf16x4 __attribute__((ext_vector_type(4)));
typedef __bf16 bf16x8 __attribute__((ext_vector_type(8)));
typedef float  f32x4  __attribute__((ext_vector_type(4)));

static constexpr int S_LEN = 4096;
static constexpr int D_DIM = 64;
static constexpr int H_NUM = 16;
static constexpr int BT    = 64;
static constexpr float QSCALE = 0.18033688011112042f;  // (1/sqrt(64)) * log2(e)
static constexpr float MB2    = 12.0f;  // fixed softmax shift (base-2)

__device__ __forceinline__ float fexp2(float x) {
#if __has_builtin(__builtin_amdgcn_exp2f)
  return __builtin_amdgcn_exp2f(x);   // raw v_exp_f32 (r10-proven)
#else
  return exp2f(x);
#endif
}

// ---- prepack: VERBATIM from r21 (proven). K and V in fragment-order.
// K: kq[((h*64+ts)*8 + g)*512 + l*8 + j], g = ct*2+kk ->
//    K^T[t = ts*64 + ct*16 + (l&15)][d = kk*32 + (l>>4)*8 + j].
// V: vq[((h*64+ts)*8 + f)*512 + l*8 + j], f = kt*4+nt ->
//    V^T[d = nt*16+(l&15)][t = kt*32+(j>>2)*16+(l>>4)*4+(j&3)].
__global__ __launch_bounds__(256)
void prepack(const float* __restrict__ kg, const float* __restrict__ vg,
             bf16_t* __restrict__ kq, bf16_t* __restrict__ vq) {
  __shared__ bf16_t tk[64][72];   // K^T tile [s][d]
  __shared__ bf16_t tv[64][72];   // V tile   [t][d]
  const int tid = threadIdx.x;
  const int h = blockIdx.x >> 6, sb = blockIdx.x & 63;
  const int s0 = sb * 64;
  const float* kh = kg + (size_t)h * D_DIM * S_LEN;
  const float* vh = vg + (size_t)h * S_LEN * D_DIM;

  #pragma unroll
  for (int it = 0; it < 4; ++it) {
    const int d = (tid >> 4) + it * 16;
    const int s = (tid & 15) * 4;
    const f32x4 x = *(const f32x4*)(kh + (size_t)d * S_LEN + s0 + s);  // K[d][s0+s..]
    #pragma unroll
    for (int i = 0; i < 4; ++i) tk[s + i][d] = (bf16_t)x[i];
    const f32x4 y = *(const f32x4*)(vh + (size_t)(s0 + d) * D_DIM + s); // V[s0+d][s..]
    bf16x4 yb;
    #pragma unroll
    for (int i = 0; i < 4; ++i) yb[i] = (bf16_t)y[i];
    *(bf16x4*)&tv[d][s] = yb;
  }
  __syncthreads();

  // K out, fragment-order
  {
    const int g  = tid >> 5;          // 0..7 = ct*2+kk
    const int ct = g >> 1, kk = g & 1;
    const int l0 = (tid & 31) * 2;    // lanes l0, l0+1
    #pragma unroll
    for (int li = 0; li < 2; ++li) {
      const int l = l0 + li;
      const int colv = l & 15, quadv = l >> 4;
      bf16x8 w;
      #pragma unroll
      for (int j = 0; j < 8; ++j)
        w[j] = tk[ct * 16 + colv][kk * 32 + quadv * 8 + j];
      *(bf16x8*)(kq + (((size_t)(h * 64 + sb) * 8 + g) * 512 + l * 8)) = w;
    }
  }
  // V out, fragment-order
  {
    const int f  = tid >> 5;          // 0..7
    const int kt = f >> 2, nt = f & 3;
    const int l0 = (tid & 31) * 2;    // lanes l0, l0+1
    #pragma unroll
    for (int li = 0; li < 2; ++li) {
      const int l = l0 + li;
      const int colv = l & 15, quadv = l >> 4;
      const int d = nt * 16 + colv;
      bf16x8 w;
      #pragma unroll
      for (int j = 0; j < 8; ++j) {
        const int t = kt * 32 + (j >> 2) * 16 + quadv * 4 + (j & 3);
        w[j] = tv[t][d];
      }
      *(bf16x8*)(vq + (((size_t)(h * 64 + sb) * 8 + f) * 512 + l * 8)) = w;
    }
  }
}

// S^T flash attention, causal, fixed-max softmax. r22 = r21 (barrier-free
// k-loop, fragment-order global K/V, wave = t-slice a x q-half b, additive
// t-slice merge) + EXPLICIT 1-deep register pipeline: step s+1's 8 fragments
// are loaded into the alternate NAMED register set before computing step s
// (unroll-2 A/B rotation; unconditional loads with tile index clamped to qt
// -> no conditional register phis, addresses always in-bounds). With no
// barrier and no LDS in the loop this is a pure-register pipeline -- the
// r11/r12 cross-BARRIER hazard class does not apply. L2 latency (~200-500cy)
// now hides under the previous step's QK^T+softmax+PV (~400cy issue).
__global__ __launch_bounds__(256, 4)
void attn_fwd(const float* __restrict__ qg, const bf16_t* __restrict__ kq,
              const bf16_t* __restrict__ vq, float* __restrict__ og) {
  __shared__ __align__(16) float obuf[2][4][2][64][4];  // [b][nt][jq][lane][r] 16KB
  __shared__ float lbuf[2][2][64];                       // [b][jq][lane] 1KB

  const int tid  = threadIdx.x;
  const int wave = tid >> 6;
  const int lane = tid & 63;
  const int col  = lane & 15;
  const int quad = lane >> 4;
  const int a    = wave & 1;    // t-slice
  const int b    = wave >> 1;   // q-half

  const int h  = blockIdx.x & 15;
  const int jb = blockIdx.x >> 4;                  // 0..63
  const int m  = jb & 15;
  const int k4 = jb >> 4;                          // 0..3
  const int qt = (k4 == 0) ? (63 - m) : (k4 == 1) ? m : (k4 == 2) ? (32 + m) : (31 - m);
  const int qbase = qt * 64;

  const float*  qh  = qg + (size_t)h * S_LEN * D_DIM;
  const bf16_t* kqh = kq + (size_t)h * 64 * 8 * 512;
  const bf16_t* vqh = vq + (size_t)h * 64 * 8 * 512;
  float*        oh  = og + (size_t)h * S_LEN * D_DIM;

  // ---- Q^T B-fragments: 32 rows (2 jq), hoisted out of the k-loop ----
  bf16x8 qb[2][2];   // [jq][kk]
  #pragma unroll
  for (int jq = 0; jq < 2; ++jq) {
    const float* qp = qh + (size_t)(qbase + b * 32 + jq * 16 + col) * D_DIM;
    #pragma unroll
    for (int kk = 0; kk < 2; ++kk) {
      f32x4 lo = *(const f32x4*)(qp + kk * 32 + quad * 8);
      f32x4 hi = *(const f32x4*)(qp + kk * 32 + quad * 8 + 4);
      #pragma unroll
      for (int j = 0; j < 4; ++j) {
        qb[jq][kk][j]     = (bf16_t)(lo[j] * QSCALE);
        qb[jq][kk][j + 4] = (bf16_t)(hi[j] * QSCALE);
      }
    }
  }

  f32x4 acc[4][2];   // [nt][jq]
  #pragma unroll
  for (int nt = 0; nt < 4; ++nt)
    #pragma unroll
    for (int jq = 0; jq < 2; ++jq) acc[nt][jq] = (f32x4){0.f, 0.f, 0.f, 0.f};
  float l_i[2] = {0.f, 0.f};

  // per-wave fragment bases (fragment-order: tile stride 4096 elems)
  const bf16_t* kwb = kqh + (size_t)(a * 4) * 512 + (size_t)lane * 8;
  const bf16_t* vwb = vqh + (size_t)(a * 4) * 512 + (size_t)lane * 8;

  const int nsteps = qt + 1;

  // one compute step on a named fragment set (fully inlined)
  auto STEP = [&](const bf16x8& k00, const bf16x8& k01,
                  const bf16x8& k10, const bf16x8& k11,
                  const bf16x8& v0, const bf16x8& v1,
                  const bf16x8& v2, const bf16x8& v3, int s) {
    f32x4 sc_[2][2];   // [ct][jq]
    #pragma unroll
    for (int ct = 0; ct < 2; ++ct)
      #pragma unroll
      for (int jq = 0; jq < 2; ++jq) sc_[ct][jq] = (f32x4){-MB2, -MB2, -MB2, -MB2};
    __builtin_amdgcn_s_setprio(1);
    sc_[0][0] = __builtin_amdgcn_mfma_f32_16x16x32_bf16(k00, qb[0][0], sc_[0][0], 0, 0, 0);
    sc_[0][1] = __builtin_amdgcn_mfma_f32_16x16x32_bf16(k00, qb[1][0], sc_[0][1], 0, 0, 0);
    sc_[1][0] = __builtin_amdgcn_mfma_f32_16x16x32_bf16(k10, qb[0][0], sc_[1][0], 0, 0, 0);
    sc_[1][1] = __builtin_amdgcn_mfma_f32_16x16x32_bf16(k10, qb[1][0], sc_[1][1], 0, 0, 0);
    sc_[0][0] = __builtin_amdgcn_mfma_f32_16x16x32_bf16(k01, qb[0][1], sc_[0][0], 0, 0, 0);
    sc_[0][1] = __builtin_amdgcn_mfma_f32_16x16x32_bf16(k01, qb[1][1], sc_[0][1], 0, 0, 0);
    sc_[1][0] = __builtin_amdgcn_mfma_f32_16x16x32_bf16(k11, qb[0][1], sc_[1][0], 0, 0, 0);
    sc_[1][1] = __builtin_amdgcn_mfma_f32_16x16x32_bf16(k11, qb[1][1], sc_[1][1], 0, 0, 0);
    __builtin_amdgcn_s_setprio(0);

    if (s == qt) {   // diagonal step: mask (block-uniform branch)
      #pragma unroll
      for (int ct = 0; ct < 2; ++ct)
        #pragma unroll
        for (int jq = 0; jq < 2; ++jq)
          #pragma unroll
          for (int r = 0; r < 4; ++r)
            sc_[ct][jq][r] = (a * 32 + ct * 16 + quad * 4 + r > b * 32 + jq * 16 + col)
                             ? -1e30f : sc_[ct][jq][r];
    }

    bf16x8 pfrag[2];   // [jq]
    #pragma unroll
    for (int jq = 0; jq < 2; ++jq) {
      float rs0 = 0.f, rs1 = 0.f;
      #pragma unroll
      for (int r = 0; r < 4; ++r) {
        const float p0 = fexp2(sc_[0][jq][r]);
        const float p1 = fexp2(sc_[1][jq][r]);
        rs0 += p0; rs1 += p1;
        pfrag[jq][r]     = (bf16_t)p0;
        pfrag[jq][r + 4] = (bf16_t)p1;
      }
      l_i[jq] += rs0 + rs1;
    }

    __builtin_amdgcn_s_setprio(1);
    acc[0][0] = __builtin_amdgcn_mfma_f32_16x16x32_bf16(v0, pfrag[0], acc[0][0], 0, 0, 0);
    acc[0][1] = __builtin_amdgcn_mfma_f32_16x16x32_bf16(v0, pfrag[1], acc[0][1], 0, 0, 0);
    acc[1][0] = __builtin_amdgcn_mfma_f32_16x16x32_bf16(v1, pfrag[0], acc[1][0], 0, 0, 0);
    acc[1][1] = __builtin_amdgcn_mfma_f32_16x16x32_bf16(v1, pfrag[1], acc[1][1], 0, 0, 0);
    acc[2][0] = __builtin_amdgcn_mfma_f32_16x16x32_bf16(v2, pfrag[0], acc[2][0], 0, 0, 0);
    acc[2][1] = __builtin_amdgcn_mfma_f32_16x16x32_bf16(v2, pfrag[1], acc[2][1], 0, 0, 0);
    acc[3][0] = __builtin_amdgcn_mfma_f32_16x16x32_bf16(v3, pfrag[0], acc[3][0], 0, 0, 0);
    acc[3][1] = __builtin_amdgcn_mfma_f32_16x16x32_bf16(v3, pfrag[1], acc[3][1], 0, 0, 0);
    __builtin_amdgcn_s_setprio(0);
  };

  // ---- prologue: load step-0 fragments into set A ----
  bf16x8 kA00, kA01, kA10, kA11, vA0, vA1, vA2, vA3;
  {
    const bf16_t* kb = kwb;
    const bf16_t* vb = vwb;
    kA00 = *(const bf16x8*)(kb);
    kA01 = *(const bf16x8*)(kb + 512);
    kA10 = *(const bf16x8*)(kb + 1024);
    kA11 = *(const bf16x8*)(kb + 1536);
    vA0  = *(const bf16x8*)(vb);
    vA1  = *(const bf16x8*)(vb + 512);
    vA2  = *(const bf16x8*)(vb + 1024);
    vA3  = *(const bf16x8*)(vb + 1536);
  }

  for (int s = 0; s < nsteps; s += 2) {
    // ---- prefetch s+1 into set B (tile clamped to qt: in-bounds, no phi) ----
    const int sn1 = (s + 1 <= qt) ? (s + 1) : qt;
    const bf16_t* kb1 = kwb + (size_t)sn1 * 4096;
    const bf16_t* vb1 = vwb + (size_t)sn1 * 4096;
    bf16x8 kB00 = *(const bf16x8*)(kb1);
    bf16x8 kB01 = *(const bf16x8*)(kb1 + 512);
    bf16x8 kB10 = *(const bf16x8*)(kb1 + 1024);
    bf16x8 kB11 = *(const bf16x8*)(kb1 + 1536);
    bf16x8 vB0  = *(const bf16x8*)(vb1);
    bf16x8 vB1  = *(const bf16x8*)(vb1 + 512);
    bf16x8 vB2  = *(const bf16x8*)(vb1 + 1024);
    bf16x8 vB3  = *(const bf16x8*)(vb1 + 1536);

    STEP(kA00, kA01, kA10, kA11, vA0, vA1, vA2, vA3, s);

    if (s + 1 >= nsteps) break;

    // ---- prefetch s+2 into set A ----
    const int sn2 = (s + 2 <= qt) ? (s + 2) : qt;
    const bf16_t* kb2 = kwb + (size_t)sn2 * 4096;
    const bf16_t* vb2 = vwb + (size_t)sn2 * 4096;
    kA00 = *(const bf16x8*)(kb2);
    kA01 = *(const bf16x8*)(kb2 + 512);
    kA10 = *(const bf16x8*)(kb2 + 1024);
    kA11 = *(const bf16x8*)(kb2 + 1536);
    vA0  = *(const bf16x8*)(vb2);
    vA1  = *(const bf16x8*)(vb2 + 512);
    vA2  = *(const bf16x8*)(vb2 + 1024);
    vA3  = *(const bf16x8*)(vb2 + 1536);

    STEP(kB00, kB01, kB10, kB11, vB0, vB1, vB2, vB3, s + 1);
  }

  // ---- cross-quad l reduction (within wave) ----
  float l0 = l_i[0];
  l0 += __shfl_xor(l0, 16);
  l0 += __shfl_xor(l0, 32);
  float l1 = l_i[1];
  l1 += __shfl_xor(l1, 16);
  l1 += __shfl_xor(l1, 32);

  // ---- additive t-slice merge: a=1 dumps, barrier, a=0 merges+stores ----
  if (a == 1) {
    #pragma unroll
    for (int nt = 0; nt < 4; ++nt)
      #pragma unroll
      for (int jq = 0; jq < 2; ++jq)
        *(f32x4*)&obuf[b][nt][jq][lane][0] = acc[nt][jq];
    lbuf[b][0][lane] = l0;
    lbuf[b][1][lane] = l1;
  }
  __syncthreads();
  if (a == 0) {
    const float invl0 = 1.0f / (l0 + lbuf[b][0][lane]);
    const float invl1 = 1.0f / (l1 + lbuf[b][1][lane]);
    #pragma unroll
    for (int nt = 0; nt < 4; ++nt) {
      #pragma unroll
      for (int jq = 0; jq < 2; ++jq) {
        const f32x4 part = *(const f32x4*)&obuf[b][nt][jq][lane][0];
        const float invl = jq ? invl1 : invl0;
        f32x4 o;
        #pragma unroll
        for (int r = 0; r < 4; ++r) o[r] = (acc[nt][jq][r] + part[r]) * invl;
        float* op = oh + (size_t)(qbase + b * 32 + jq * 16 + col) * D_DIM + nt * 16 + quad * 4;
        *(f32x4*)op = o;
      }
    }
  }
}

extern "C" void kernel_launch(void* const* d_in, const int* in_sizes, int n_in,
                              void* d_out, int out_size, void* d_ws, size_t ws_size,
                              hipStream_t stream) {
  const float* q = (const float*)d_in[0];
  const float* k = (const float*)d_in[1];
  const float* v = (const float*)d_in[2];
  float* out = (float*)d_out;

  // ws: [0,8M) kq bf16 (fragment-order) | [8M,16M) vq bf16 (fragment-order)
  const size_t KB = (size_t)H_NUM * S_LEN * D_DIM * 2;   // 8,388,608
  bf16_t* kq = (bf16_t*)d_ws;
  bf16_t* vq = (bf16_t*)((char*)d_ws + KB);

  prepack<<<dim3(H_NUM * 64), dim3(256), 0, stream>>>(k, v, kq, vq);
  attn_fwd<<<dim3(H_NUM * 64), dim3(256), 0, stream>>>(q, kq, vq, out);
}

// Round 13
// 134.679 us; speedup vs baseline: 1.3203x; 1.3203x over previous
//
#include <hip/hip_runtime.h>
#include <hip/hip_bf16.h>
#include <math.h>

typedef __bf16 bf16_t;
typedef __bf16 bf16x4 __attribute__((ext_vector_type(4)));
typedef __bf16 bf16x8 __attribute__((ext_vector_type(8)));
typedef float  f32x4  __attribute__((ext_vector_type(4)));

static constexpr int S_LEN = 4096;
static constexpr int D_DIM = 64;
static constexpr int H_NUM = 16;
static constexpr int BT    = 64;
static constexpr float QSCALE = 0.18033688011112042f;  // (1/sqrt(64)) * log2(e)
static constexpr float MB2    = 12.0f;  // fixed softmax shift (base-2)

__device__ __forceinline__ float fexp2(float x) {
#if __has_builtin(__builtin_amdgcn_exp2f)
  return __builtin_amdgcn_exp2f(x);   // raw v_exp_f32 (r10-proven)
#else
  return exp2f(x);
#endif
}

// ---- prepack: VERBATIM from r21 (proven). K and V in fragment-order.
// K: kq[((h*64+ts)*8 + g)*512 + l*8 + j], g = ct*2+kk ->
//    K^T[t = ts*64 + ct*16 + (l&15)][d = kk*32 + (l>>4)*8 + j].
// V: vq[((h*64+ts)*8 + f)*512 + l*8 + j], f = kt*4+nt ->
//    V^T[d = nt*16+(l&15)][t = kt*32+(j>>2)*16+(l>>4)*4+(j&3)].
__global__ __launch_bounds__(256)
void prepack(const float* __restrict__ kg, const float* __restrict__ vg,
             bf16_t* __restrict__ kq, bf16_t* __restrict__ vq) {
  __shared__ bf16_t tk[64][72];   // K^T tile [s][d]
  __shared__ bf16_t tv[64][72];   // V tile   [t][d]
  const int tid = threadIdx.x;
  const int h = blockIdx.x >> 6, sb = blockIdx.x & 63;
  const int s0 = sb * 64;
  const float* kh = kg + (size_t)h * D_DIM * S_LEN;
  const float* vh = vg + (size_t)h * S_LEN * D_DIM;

  #pragma unroll
  for (int it = 0; it < 4; ++it) {
    const int d = (tid >> 4) + it * 16;
    const int s = (tid & 15) * 4;
    const f32x4 x = *(const f32x4*)(kh + (size_t)d * S_LEN + s0 + s);  // K[d][s0+s..]
    #pragma unroll
    for (int i = 0; i < 4; ++i) tk[s + i][d] = (bf16_t)x[i];
    const f32x4 y = *(const f32x4*)(vh + (size_t)(s0 + d) * D_DIM + s); // V[s0+d][s..]
    bf16x4 yb;
    #pragma unroll
    for (int i = 0; i < 4; ++i) yb[i] = (bf16_t)y[i];
    *(bf16x4*)&tv[d][s] = yb;
  }
  __syncthreads();

  // K out, fragment-order
  {
    const int g  = tid >> 5;          // 0..7 = ct*2+kk
    const int ct = g >> 1, kk = g & 1;
    const int l0 = (tid & 31) * 2;    // lanes l0, l0+1
    #pragma unroll
    for (int li = 0; li < 2; ++li) {
      const int l = l0 + li;
      const int colv = l & 15, quadv = l >> 4;
      bf16x8 w;
      #pragma unroll
      for (int j = 0; j < 8; ++j)
        w[j] = tk[ct * 16 + colv][kk * 32 + quadv * 8 + j];
      *(bf16x8*)(kq + (((size_t)(h * 64 + sb) * 8 + g) * 512 + l * 8)) = w;
    }
  }
  // V out, fragment-order
  {
    const int f  = tid >> 5;          // 0..7
    const int kt = f >> 2, nt = f & 3;
    const int l0 = (tid & 31) * 2;    // lanes l0, l0+1
    #pragma unroll
    for (int li = 0; li < 2; ++li) {
      const int l = l0 + li;
      const int colv = l & 15, quadv = l >> 4;
      const int d = nt * 16 + colv;
      bf16x8 w;
      #pragma unroll
      for (int j = 0; j < 8; ++j) {
        const int t = kt * 32 + (j >> 2) * 16 + quadv * 4 + (j & 3);
        w[j] = tv[t][d];
      }
      *(bf16x8*)(vq + (((size_t)(h * 64 + sb) * 8 + f) * 512 + l * 8)) = w;
    }
  }
}

// S^T flash attention, causal, fixed-max softmax. r23 = r21 BYTE-IDENTICAL
// except __launch_bounds__(256, 2).
// Diagnosis: every r13-r21 variant declared (...,4), which the compiler
// treats as a 64-VGPR cap (r17:60, r19:64, r20:64, r21:56; r22 spilled 20MB
// to scratch rather than exceed 64). r21's live set (kf+vf 64 + acc 32 +
// qb 16 + sc 16) cannot fit 64, so the compiler SINKS every load to just
// before its use -> full L2 latency exposed every step -> the ~27% issue
// utilization fixed point seen in all nine variants. (256,2) raises the cap
// to 128; actual VGPR should land 90-128, which STILL allows 4 waves/SIMD
// (m69 tier: <=128), so occupancy is unchanged while the scheduler can now
// hoist the 8 fragment loads and keep them live across QK^T+softmax.
__global__ __launch_bounds__(256, 2)
void attn_fwd(const float* __restrict__ qg, const bf16_t* __restrict__ kq,
              const bf16_t* __restrict__ vq, float* __restrict__ og) {
  __shared__ __align__(16) float obuf[2][4][2][64][4];  // [b][nt][jq][lane][r] 16KB
  __shared__ float lbuf[2][2][64];                       // [b][jq][lane] 1KB

  const int tid  = threadIdx.x;
  const int wave = tid >> 6;
  const int lane = tid & 63;
  const int col  = lane & 15;
  const int quad = lane >> 4;
  const int a    = wave & 1;    // t-slice
  const int b    = wave >> 1;   // q-half

  const int h  = blockIdx.x & 15;
  const int jb = blockIdx.x >> 4;                  // 0..63
  const int m  = jb & 15;
  const int k4 = jb >> 4;                          // 0..3
  const int qt = (k4 == 0) ? (63 - m) : (k4 == 1) ? m : (k4 == 2) ? (32 + m) : (31 - m);
  const int qbase = qt * 64;

  const float*  qh  = qg + (size_t)h * S_LEN * D_DIM;
  const bf16_t* kqh = kq + (size_t)h * 64 * 8 * 512;
  const bf16_t* vqh = vq + (size_t)h * 64 * 8 * 512;
  float*        oh  = og + (size_t)h * S_LEN * D_DIM;

  // ---- Q^T B-fragments: 32 rows (2 jq), hoisted out of the k-loop ----
  bf16x8 qb[2][2];   // [jq][kk]
  #pragma unroll
  for (int jq = 0; jq < 2; ++jq) {
    const float* qp = qh + (size_t)(qbase + b * 32 + jq * 16 + col) * D_DIM;
    #pragma unroll
    for (int kk = 0; kk < 2; ++kk) {
      f32x4 lo = *(const f32x4*)(qp + kk * 32 + quad * 8);
      f32x4 hi = *(const f32x4*)(qp + kk * 32 + quad * 8 + 4);
      #pragma unroll
      for (int j = 0; j < 4; ++j) {
        qb[jq][kk][j]     = (bf16_t)(lo[j] * QSCALE);
        qb[jq][kk][j + 4] = (bf16_t)(hi[j] * QSCALE);
      }
    }
  }

  f32x4 acc[4][2];   // [nt][jq]
  #pragma unroll
  for (int nt = 0; nt < 4; ++nt)
    #pragma unroll
    for (int jq = 0; jq < 2; ++jq) acc[nt][jq] = (f32x4){0.f, 0.f, 0.f, 0.f};
  float l_i[2] = {0.f, 0.f};

  // per-wave fragment bases (fragment-order: tile stride 4096 elems)
  const bf16_t* kwb = kqh + (size_t)(a * 4) * 512 + (size_t)lane * 8;
  const bf16_t* vwb = vqh + (size_t)(a * 4) * 512 + (size_t)lane * 8;

  const int nsteps = qt + 1;

  for (int s = 0; s < nsteps; ++s) {
    const bf16_t* kb = kwb + (size_t)s * 4096;
    const bf16_t* vb = vwb + (size_t)s * 4096;

    // ---- V fragments (kt = a), issued early: consumed after softmax ----
    const bf16x8 vf0 = *(const bf16x8*)(vb);
    const bf16x8 vf1 = *(const bf16x8*)(vb + 512);
    const bf16x8 vf2 = *(const bf16x8*)(vb + 1024);
    const bf16x8 vf3 = *(const bf16x8*)(vb + 1536);

    // ---- K fragments (coalesced 1KB each) ----
    bf16x8 kf[2][2];   // [ct][kk]
    kf[0][0] = *(const bf16x8*)(kb);
    kf[0][1] = *(const bf16x8*)(kb + 512);
    kf[1][0] = *(const bf16x8*)(kb + 1024);
    kf[1][1] = *(const bf16x8*)(kb + 1536);

    // ---- QK^T -> S^T (C init -MB2) ----
    f32x4 sc_[2][2];   // [ct][jq]
    #pragma unroll
    for (int ct = 0; ct < 2; ++ct)
      #pragma unroll
      for (int jq = 0; jq < 2; ++jq) sc_[ct][jq] = (f32x4){-MB2, -MB2, -MB2, -MB2};
    __builtin_amdgcn_s_setprio(1);
    #pragma unroll
    for (int ct = 0; ct < 2; ++ct)
      #pragma unroll
      for (int jq = 0; jq < 2; ++jq)
        #pragma unroll
        for (int kk = 0; kk < 2; ++kk)
          sc_[ct][jq] = __builtin_amdgcn_mfma_f32_16x16x32_bf16(kf[ct][kk], qb[jq][kk], sc_[ct][jq], 0, 0, 0);
    __builtin_amdgcn_s_setprio(0);

    // ---- mask (diagonal step only; block-uniform branch) ----
    if (s == qt) {
      #pragma unroll
      for (int ct = 0; ct < 2; ++ct)
        #pragma unroll
        for (int jq = 0; jq < 2; ++jq)
          #pragma unroll
          for (int r = 0; r < 4; ++r)
            sc_[ct][jq][r] = (a * 32 + ct * 16 + quad * 4 + r > b * 32 + jq * 16 + col)
                             ? -1e30f : sc_[ct][jq][r];
    }

    // ---- fixed-max softmax -> PV B-fragments (k-slot j <-> sc_[j>>2][*][j&3]) ----
    bf16x8 pfrag[2];   // [jq]
    #pragma unroll
    for (int jq = 0; jq < 2; ++jq) {
      float rs0 = 0.f, rs1 = 0.f;
      #pragma unroll
      for (int r = 0; r < 4; ++r) {
        const float p0 = fexp2(sc_[0][jq][r]);
        const float p1 = fexp2(sc_[1][jq][r]);
        rs0 += p0; rs1 += p1;
        pfrag[jq][r]     = (bf16_t)p0;
        pfrag[jq][r + 4] = (bf16_t)p1;
      }
      l_i[jq] += rs0 + rs1;
    }

    // ---- PV -> O^T partial (t-slice a) ----
    __builtin_amdgcn_s_setprio(1);
    acc[0][0] = __builtin_amdgcn_mfma_f32_16x16x32_bf16(vf0, pfrag[0], acc[0][0], 0, 0, 0);
    acc[0][1] = __builtin_amdgcn_mfma_f32_16x16x32_bf16(vf0, pfrag[1], acc[0][1], 0, 0, 0);
    acc[1][0] = __builtin_amdgcn_mfma_f32_16x16x32_bf16(vf1, pfrag[0], acc[1][0], 0, 0, 0);
    acc[1][1] = __builtin_amdgcn_mfma_f32_16x16x32_bf16(vf1, pfrag[1], acc[1][1], 0, 0, 0);
    acc[2][0] = __builtin_amdgcn_mfma_f32_16x16x32_bf16(vf2, pfrag[0], acc[2][0], 0, 0, 0);
    acc[2][1] = __builtin_amdgcn_mfma_f32_16x16x32_bf16(vf2, pfrag[1], acc[2][1], 0, 0, 0);
    acc[3][0] = __builtin_amdgcn_mfma_f32_16x16x32_bf16(vf3, pfrag[0], acc[3][0], 0, 0, 0);
    acc[3][1] = __builtin_amdgcn_mfma_f32_16x16x32_bf16(vf3, pfrag[1], acc[3][1], 0, 0, 0);
    __builtin_amdgcn_s_setprio(0);
    // NO barrier: nothing in the loop is shared between waves.
  }

  // ---- cross-quad l reduction (within wave) ----
  float l0 = l_i[0];
  l0 += __shfl_xor(l0, 16);
  l0 += __shfl_xor(l0, 32);
  float l1 = l_i[1];
  l1 += __shfl_xor(l1, 16);
  l1 += __shfl_xor(l1, 32);

  // ---- additive t-slice merge: a=1 dumps, barrier, a=0 merges+stores ----
  if (a == 1) {
    #pragma unroll
    for (int nt = 0; nt < 4; ++nt)
      #pragma unroll
      for (int jq = 0; jq < 2; ++jq)
        *(f32x4*)&obuf[b][nt][jq][lane][0] = acc[nt][jq];
    lbuf[b][0][lane] = l0;
    lbuf[b][1][lane] = l1;
  }
  __syncthreads();
  if (a == 0) {
    const float invl0 = 1.0f / (l0 + lbuf[b][0][lane]);
    const float invl1 = 1.0f / (l1 + lbuf[b][1][lane]);
    #pragma unroll
    for (int nt = 0; nt < 4; ++nt) {
      #pragma unroll
      for (int jq = 0; jq < 2; ++jq) {
        const f32x4 part = *(const f32x4*)&obuf[b][nt][jq][lane][0];
        const float invl = jq ? invl1 : invl0;
        f32x4 o;
        #pragma unroll
        for (int r = 0; r < 4; ++r) o[r] = (acc[nt][jq][r] + part[r]) * invl;
        float* op = oh + (size_t)(qbase + b * 32 + jq * 16 + col) * D_DIM + nt * 16 + quad * 4;
        *(f32x4*)op = o;
      }
    }
  }
}

extern "C" void kernel_launch(void* const* d_in, const int* in_sizes, int n_in,
                              void* d_out, int out_size, void* d_ws, size_t ws_size,
                              hipStream_t stream) {
  const float* q = (const float*)d_in[0];
  const float* k = (const float*)d_in[1];
  const float* v = (const float*)d_in[2];
  float* out = (float*)d_out;

  // ws: [0,8M) kq bf16 (fragment-order) | [8M,16M) vq bf16 (fragment-order)
  const size_t KB = (size_t)H_NUM * S_LEN * D_DIM * 2;   // 8,388,608
  bf16_t* kq = (bf16_t*)d_ws;
  bf16_t* vq = (bf16_t*)((char*)d_ws + KB);

  prepack<<<dim3(H_NUM * 64), dim3(256), 0, stream>>>(k, v, kq, vq);
  attn_fwd<<<dim3(H_NUM * 64), dim3(256), 0, stream>>>(q, kq, vq, out);
}

// Round 14
// 130.986 us; speedup vs baseline: 1.3576x; 1.0282x over previous
//
#include <hip/hip_runtime.h>
#include <hip/hip_bf16.h>
#include <math.h>

typedef __bf16 bf16_t;
typedef __bf16 bf16x4 __attribute__((ext_vector_type(4)));
typedef __bf16 bf16x8 __attribute__((ext_vector_type(8)));
typedef float  f32x4  __attribute__((ext_vector_type(4)));

static constexpr int S_LEN = 4096;
static constexpr int D_DIM = 64;
static constexpr int H_NUM = 16;
static constexpr int BT    = 64;
static constexpr float QSCALE = 0.18033688011112042f;  // (1/sqrt(64)) * log2(e)
static constexpr float MB2    = 12.0f;  // fixed softmax shift (base-2)

__device__ __forceinline__ float fexp2(float x) {
#if __has_builtin(__builtin_amdgcn_exp2f)
  return __builtin_amdgcn_exp2f(x);   // raw v_exp_f32 (r10-proven)
#else
  return exp2f(x);
#endif
}

// ---- prepack: VERBATIM from r21 (proven). K and V in fragment-order.
// K: kq[((h*64+ts)*8 + g)*512 + l*8 + j], g = ct*2+kk ->
//    K^T[t = ts*64 + ct*16 + (l&15)][d = kk*32 + (l>>4)*8 + j].
// V: vq[((h*64+ts)*8 + f)*512 + l*8 + j], f = kt*4+nt ->
//    V^T[d = nt*16+(l&15)][t = kt*32+(j>>2)*16+(l>>4)*4+(j&3)].
__global__ __launch_bounds__(256)
void prepack(const float* __restrict__ kg, const float* __restrict__ vg,
             bf16_t* __restrict__ kq, bf16_t* __restrict__ vq) {
  __shared__ bf16_t tk[64][72];   // K^T tile [s][d]
  __shared__ bf16_t tv[64][72];   // V tile   [t][d]
  const int tid = threadIdx.x;
  const int h = blockIdx.x >> 6, sb = blockIdx.x & 63;
  const int s0 = sb * 64;
  const float* kh = kg + (size_t)h * D_DIM * S_LEN;
  const float* vh = vg + (size_t)h * S_LEN * D_DIM;

  #pragma unroll
  for (int it = 0; it < 4; ++it) {
    const int d = (tid >> 4) + it * 16;
    const int s = (tid & 15) * 4;
    const f32x4 x = *(const f32x4*)(kh + (size_t)d * S_LEN + s0 + s);  // K[d][s0+s..]
    #pragma unroll
    for (int i = 0; i < 4; ++i) tk[s + i][d] = (bf16_t)x[i];
    const f32x4 y = *(const f32x4*)(vh + (size_t)(s0 + d) * D_DIM + s); // V[s0+d][s..]
    bf16x4 yb;
    #pragma unroll
    for (int i = 0; i < 4; ++i) yb[i] = (bf16_t)y[i];
    *(bf16x4*)&tv[d][s] = yb;
  }
  __syncthreads();

  // K out, fragment-order
  {
    const int g  = tid >> 5;          // 0..7 = ct*2+kk
    const int ct = g >> 1, kk = g & 1;
    const int l0 = (tid & 31) * 2;    // lanes l0, l0+1
    #pragma unroll
    for (int li = 0; li < 2; ++li) {
      const int l = l0 + li;
      const int colv = l & 15, quadv = l >> 4;
      bf16x8 w;
      #pragma unroll
      for (int j = 0; j < 8; ++j)
        w[j] = tk[ct * 16 + colv][kk * 32 + quadv * 8 + j];
      *(bf16x8*)(kq + (((size_t)(h * 64 + sb) * 8 + g) * 512 + l * 8)) = w;
    }
  }
  // V out, fragment-order
  {
    const int f  = tid >> 5;          // 0..7
    const int kt = f >> 2, nt = f & 3;
    const int l0 = (tid & 31) * 2;    // lanes l0, l0+1
    #pragma unroll
    for (int li = 0; li < 2; ++li) {
      const int l = l0 + li;
      const int colv = l & 15, quadv = l >> 4;
      const int d = nt * 16 + colv;
      bf16x8 w;
      #pragma unroll
      for (int j = 0; j < 8; ++j) {
        const int t = kt * 32 + (j >> 2) * 16 + quadv * 4 + (j & 3);
        w[j] = tv[t][d];
      }
      *(bf16x8*)(vq + (((size_t)(h * 64 + sb) * 8 + f) * 512 + l * 8)) = w;
    }
  }
}

// S^T flash attention, causal, fixed-max softmax. r24 = r23 (barrier-free
// k-loop, fragment-order global K/V, wave = t-slice a x q-half b, additive
// t-slice merge, launch_bounds(256,2)) + FORCED K-only register pipeline:
// r23 proved the compiler sinks loads to uses even with VGPR headroom
// (VGPR stayed 56 under a 256 cap), and r22 proved it RESPECTS explicit
// named cross-iteration sets (it spilled rather than re-sink). So force the
// hoist with the minimal set that fits the 128-VGPR/4-wave tier: K frags
// only (used immediately after load -- the exposed-latency operand), A/B
// named sets, unroll-2, clamped prefetch index (no conditional phis).
// V stays same-iteration (issued at top, ~400cy QK^T+softmax cover).
// Est. live: acc32+qb16+kA16+kB16+vf16+sc16+pfrag4+addr ~= 122 <= 128.
__global__ __launch_bounds__(256, 2)
void attn_fwd(const float* __restrict__ qg, const bf16_t* __restrict__ kq,
              const bf16_t* __restrict__ vq, float* __restrict__ og) {
  __shared__ __align__(16) float obuf[2][4][2][64][4];  // [b][nt][jq][lane][r] 16KB
  __shared__ float lbuf[2][2][64];                       // [b][jq][lane] 1KB

  const int tid  = threadIdx.x;
  const int wave = tid >> 6;
  const int lane = tid & 63;
  const int col  = lane & 15;
  const int quad = lane >> 4;
  const int a    = wave & 1;    // t-slice
  const int b    = wave >> 1;   // q-half

  const int h  = blockIdx.x & 15;
  const int jb = blockIdx.x >> 4;                  // 0..63
  const int m  = jb & 15;
  const int k4 = jb >> 4;                          // 0..3
  const int qt = (k4 == 0) ? (63 - m) : (k4 == 1) ? m : (k4 == 2) ? (32 + m) : (31 - m);
  const int qbase = qt * 64;

  const float*  qh  = qg + (size_t)h * S_LEN * D_DIM;
  const bf16_t* kqh = kq + (size_t)h * 64 * 8 * 512;
  const bf16_t* vqh = vq + (size_t)h * 64 * 8 * 512;
  float*        oh  = og + (size_t)h * S_LEN * D_DIM;

  // ---- Q^T B-fragments: 32 rows (2 jq), hoisted out of the k-loop ----
  bf16x8 qb[2][2];   // [jq][kk]
  #pragma unroll
  for (int jq = 0; jq < 2; ++jq) {
    const float* qp = qh + (size_t)(qbase + b * 32 + jq * 16 + col) * D_DIM;
    #pragma unroll
    for (int kk = 0; kk < 2; ++kk) {
      f32x4 lo = *(const f32x4*)(qp + kk * 32 + quad * 8);
      f32x4 hi = *(const f32x4*)(qp + kk * 32 + quad * 8 + 4);
      #pragma unroll
      for (int j = 0; j < 4; ++j) {
        qb[jq][kk][j]     = (bf16_t)(lo[j] * QSCALE);
        qb[jq][kk][j + 4] = (bf16_t)(hi[j] * QSCALE);
      }
    }
  }

  f32x4 acc[4][2];   // [nt][jq]
  #pragma unroll
  for (int nt = 0; nt < 4; ++nt)
    #pragma unroll
    for (int jq = 0; jq < 2; ++jq) acc[nt][jq] = (f32x4){0.f, 0.f, 0.f, 0.f};
  float l_i[2] = {0.f, 0.f};

  // per-wave fragment bases (fragment-order: tile stride 4096 elems)
  const bf16_t* kwb = kqh + (size_t)(a * 4) * 512 + (size_t)lane * 8;
  const bf16_t* vwb = vqh + (size_t)(a * 4) * 512 + (size_t)lane * 8;

  const int nsteps = qt + 1;

  // one compute step on named K set + named V set
  auto STEP = [&](const bf16x8& k00, const bf16x8& k01,
                  const bf16x8& k10, const bf16x8& k11,
                  const bf16x8& v0, const bf16x8& v1,
                  const bf16x8& v2, const bf16x8& v3, int s) {
    f32x4 sc_[2][2];   // [ct][jq]
    #pragma unroll
    for (int ct = 0; ct < 2; ++ct)
      #pragma unroll
      for (int jq = 0; jq < 2; ++jq) sc_[ct][jq] = (f32x4){-MB2, -MB2, -MB2, -MB2};
    __builtin_amdgcn_s_setprio(1);
    sc_[0][0] = __builtin_amdgcn_mfma_f32_16x16x32_bf16(k00, qb[0][0], sc_[0][0], 0, 0, 0);
    sc_[0][1] = __builtin_amdgcn_mfma_f32_16x16x32_bf16(k00, qb[1][0], sc_[0][1], 0, 0, 0);
    sc_[1][0] = __builtin_amdgcn_mfma_f32_16x16x32_bf16(k10, qb[0][0], sc_[1][0], 0, 0, 0);
    sc_[1][1] = __builtin_amdgcn_mfma_f32_16x16x32_bf16(k10, qb[1][0], sc_[1][1], 0, 0, 0);
    sc_[0][0] = __builtin_amdgcn_mfma_f32_16x16x32_bf16(k01, qb[0][1], sc_[0][0], 0, 0, 0);
    sc_[0][1] = __builtin_amdgcn_mfma_f32_16x16x32_bf16(k01, qb[1][1], sc_[0][1], 0, 0, 0);
    sc_[1][0] = __builtin_amdgcn_mfma_f32_16x16x32_bf16(k11, qb[0][1], sc_[1][0], 0, 0, 0);
    sc_[1][1] = __builtin_amdgcn_mfma_f32_16x16x32_bf16(k11, qb[1][1], sc_[1][1], 0, 0, 0);
    __builtin_amdgcn_s_setprio(0);

    if (s == qt) {   // diagonal step: mask (block-uniform branch)
      #pragma unroll
      for (int ct = 0; ct < 2; ++ct)
        #pragma unroll
        for (int jq = 0; jq < 2; ++jq)
          #pragma unroll
          for (int r = 0; r < 4; ++r)
            sc_[ct][jq][r] = (a * 32 + ct * 16 + quad * 4 + r > b * 32 + jq * 16 + col)
                             ? -1e30f : sc_[ct][jq][r];
    }

    bf16x8 pfrag[2];   // [jq]
    #pragma unroll
    for (int jq = 0; jq < 2; ++jq) {
      float rs0 = 0.f, rs1 = 0.f;
      #pragma unroll
      for (int r = 0; r < 4; ++r) {
        const float p0 = fexp2(sc_[0][jq][r]);
        const float p1 = fexp2(sc_[1][jq][r]);
        rs0 += p0; rs1 += p1;
        pfrag[jq][r]     = (bf16_t)p0;
        pfrag[jq][r + 4] = (bf16_t)p1;
      }
      l_i[jq] += rs0 + rs1;
    }

    __builtin_amdgcn_s_setprio(1);
    acc[0][0] = __builtin_amdgcn_mfma_f32_16x16x32_bf16(v0, pfrag[0], acc[0][0], 0, 0, 0);
    acc[0][1] = __builtin_amdgcn_mfma_f32_16x16x32_bf16(v0, pfrag[1], acc[0][1], 0, 0, 0);
    acc[1][0] = __builtin_amdgcn_mfma_f32_16x16x32_bf16(v1, pfrag[0], acc[1][0], 0, 0, 0);
    acc[1][1] = __builtin_amdgcn_mfma_f32_16x16x32_bf16(v1, pfrag[1], acc[1][1], 0, 0, 0);
    acc[2][0] = __builtin_amdgcn_mfma_f32_16x16x32_bf16(v2, pfrag[0], acc[2][0], 0, 0, 0);
    acc[2][1] = __builtin_amdgcn_mfma_f32_16x16x32_bf16(v2, pfrag[1], acc[2][1], 0, 0, 0);
    acc[3][0] = __builtin_amdgcn_mfma_f32_16x16x32_bf16(v3, pfrag[0], acc[3][0], 0, 0, 0);
    acc[3][1] = __builtin_amdgcn_mfma_f32_16x16x32_bf16(v3, pfrag[1], acc[3][1], 0, 0, 0);
    __builtin_amdgcn_s_setprio(0);
  };

  // ---- prologue: K fragments of step 0 into set A ----
  bf16x8 kA00 = *(const bf16x8*)(kwb);
  bf16x8 kA01 = *(const bf16x8*)(kwb + 512);
  bf16x8 kA10 = *(const bf16x8*)(kwb + 1024);
  bf16x8 kA11 = *(const bf16x8*)(kwb + 1536);

  for (int s = 0; s < nsteps; s += 2) {
    // ---- V of step s (same-iteration; covered by QK^T+softmax) ----
    const bf16_t* vbs = vwb + (size_t)s * 4096;
    const bf16x8 vA0 = *(const bf16x8*)(vbs);
    const bf16x8 vA1 = *(const bf16x8*)(vbs + 512);
    const bf16x8 vA2 = *(const bf16x8*)(vbs + 1024);
    const bf16x8 vA3 = *(const bf16x8*)(vbs + 1536);

    // ---- prefetch K of step s+1 into set B (clamped: in-bounds, no phi) ----
    const int sn1 = (s + 1 <= qt) ? (s + 1) : qt;
    const bf16_t* kb1 = kwb + (size_t)sn1 * 4096;
    bf16x8 kB00 = *(const bf16x8*)(kb1);
    bf16x8 kB01 = *(const bf16x8*)(kb1 + 512);
    bf16x8 kB10 = *(const bf16x8*)(kb1 + 1024);
    bf16x8 kB11 = *(const bf16x8*)(kb1 + 1536);

    STEP(kA00, kA01, kA10, kA11, vA0, vA1, vA2, vA3, s);

    if (s + 1 >= nsteps) break;

    // ---- V of step s+1 ----
    const bf16_t* vbs1 = vwb + (size_t)(s + 1) * 4096;
    const bf16x8 vB0 = *(const bf16x8*)(vbs1);
    const bf16x8 vB1 = *(const bf16x8*)(vbs1 + 512);
    const bf16x8 vB2 = *(const bf16x8*)(vbs1 + 1024);
    const bf16x8 vB3 = *(const bf16x8*)(vbs1 + 1536);

    // ---- prefetch K of step s+2 into set A (clamped) ----
    const int sn2 = (s + 2 <= qt) ? (s + 2) : qt;
    const bf16_t* kb2 = kwb + (size_t)sn2 * 4096;
    kA00 = *(const bf16x8*)(kb2);
    kA01 = *(const bf16x8*)(kb2 + 512);
    kA10 = *(const bf16x8*)(kb2 + 1024);
    kA11 = *(const bf16x8*)(kb2 + 1536);

    STEP(kB00, kB01, kB10, kB11, vB0, vB1, vB2, vB3, s + 1);
  }

  // ---- cross-quad l reduction (within wave) ----
  float l0 = l_i[0];
  l0 += __shfl_xor(l0, 16);
  l0 += __shfl_xor(l0, 32);
  float l1 = l_i[1];
  l1 += __shfl_xor(l1, 16);
  l1 += __shfl_xor(l1, 32);

  // ---- additive t-slice merge: a=1 dumps, barrier, a=0 merges+stores ----
  if (a == 1) {
    #pragma unroll
    for (int nt = 0; nt < 4; ++nt)
      #pragma unroll
      for (int jq = 0; jq < 2; ++jq)
        *(f32x4*)&obuf[b][nt][jq][lane][0] = acc[nt][jq];
    lbuf[b][0][lane] = l0;
    lbuf[b][1][lane] = l1;
  }
  __syncthreads();
  if (a == 0) {
    const float invl0 = 1.0f / (l0 + lbuf[b][0][lane]);
    const float invl1 = 1.0f / (l1 + lbuf[b][1][lane]);
    #pragma unroll
    for (int nt = 0; nt < 4; ++nt) {
      #pragma unroll
      for (int jq = 0; jq < 2; ++jq) {
        const f32x4 part = *(const f32x4*)&obuf[b][nt][jq][lane][0];
        const float invl = jq ? invl1 : invl0;
        f32x4 o;
        #pragma unroll
        for (int r = 0; r < 4; ++r) o[r] = (acc[nt][jq][r] + part[r]) * invl;
        float* op = oh + (size_t)(qbase + b * 32 + jq * 16 + col) * D_DIM + nt * 16 + quad * 4;
        *(f32x4*)op = o;
      }
    }
  }
}

extern "C" void kernel_launch(void* const* d_in, const int* in_sizes, int n_in,
                              void* d_out, int out_size, void* d_ws, size_t ws_size,
                              hipStream_t stream) {
  const float* q = (const float*)d_in[0];
  const float* k = (const float*)d_in[1];
  const float* v = (const float*)d_in[2];
  float* out = (float*)d_out;

  // ws: [0,8M) kq bf16 (fragment-order) | [8M,16M) vq bf16 (fragment-order)
  const size_t KB = (size_t)H_NUM * S_LEN * D_DIM * 2;   // 8,388,608
  bf16_t* kq = (bf16_t*)d_ws;
  bf16_t* vq = (bf16_t*)((char*)d_ws + KB);

  prepack<<<dim3(H_NUM * 64), dim3(256), 0, stream>>>(k, v, kq, vq);
  attn_fwd<<<dim3(H_NUM * 64), dim3(256), 0, stream>>>(q, kq, vq, out);
}